// Round 1
// baseline (120.946 us; speedup 1.0000x reference)
//
#include <hip/hip_runtime.h>

#define B_    32
#define N_    32
#define S_    52
#define C_    80
#define PLANE (S_*S_)          // 2704
#define CPB   (3*PLANE)        // 8112 cells per batch
#define BPB   16               // blocks per batch: 16 * 512 cells = 8192 >= 8112
#define NBLK  (B_*BPB)         // 512 blocks, 2 cells/thread, 256 thr/blk

// anchors / stride(=8) for S=52
__device__ __constant__ float d_aw[9] = {14.5f, 19.5f, 46.625f, 3.75f, 7.75f, 7.375f, 1.25f, 2.0f,  4.125f};
__device__ __constant__ float d_ah[9] = {11.25f,24.75f,40.75f,  7.625f,5.625f,14.875f,1.625f,3.75f, 2.875f};

__global__ void kzero(float* res) {
    if (threadIdx.x < 2) res[threadIdx.x] = 0.0f;
}
__global__ void kfix(float* res) {
    res[1] = fmaxf(res[1], 1.0f);
}

__device__ __forceinline__ float sigm(float z)  { return 1.0f / (1.0f + __expf(-z)); }
__device__ __forceinline__ float clampp(float p){ return fminf(fmaxf(p, 1e-7f), 1.0f - 1e-7f); }

__launch_bounds__(256)
__global__ void kmain(const float* __restrict__ pred,
                      const float* __restrict__ tgts,
                      float2* __restrict__ part,
                      float* __restrict__ res,
                      int use_part) {
    __shared__ float4 s_box[N_];   // ax1, ay1, ax2, ay2
    __shared__ float2 s_am[N_];    // area, bitcast(meta)  meta = key(14b) | cls<<14
    __shared__ float4 s_reg[N_];   // ttx, tty, ttw, tth
    __shared__ float  s_bls[N_];   // box_loss_scale
    __shared__ float  s_red[8];

    const int bb = (int)blockIdx.x >> 4;                       // batch (block is single-batch)
    const int r0 = (((int)blockIdx.x & 15) << 9) + (int)threadIdx.x;  // cell0, always < 7936 < CPB
    const int r1 = r0 + 256;                                   // cell1, may be >= CPB (pad tail)
    const bool v1 = (r1 < CPB);

    // cell decode
    const int a0 = r0 / PLANE, lin0 = r0 - a0*PLANE;
    const int i0 = lin0 / S_,  j0 = lin0 - i0*S_;
    const int a1t = r1 / PLANE, lin1 = r1 - a1t*PLANE;
    const int i1 = lin1 / S_,  j1 = lin1 - i1*S_;

    // issue the 10 channel loads early (coalesced); invalid cell1 aliases cell0's
    // address so loads stay in-bounds (its results are fully masked later)
    const int off0 = (bb*255 + a0*85)*PLANE + lin0;
    const int off1 = v1 ? (bb*255 + a1t*85)*PLANE + lin1 : off0;
    const float z00 = pred[off0];
    const float z01 = pred[off0 + 1*PLANE];
    const float z02 = pred[off0 + 2*PLANE];
    const float z03 = pred[off0 + 3*PLANE];
    const float z04 = pred[off0 + 4*PLANE];
    const float z10 = pred[off1];
    const float z11 = pred[off1 + 1*PLANE];
    const float z12 = pred[off1 + 2*PLANE];
    const float z13 = pred[off1 + 3*PLANE];
    const float z14 = pred[off1 + 4*PLANE];

    // stage the 32 targets of this block's (single) batch
    if ((int)threadIdx.x < N_) {
        const int n  = (int)threadIdx.x;
        const float* tp = tgts + (size_t)(bb*N_ + n)*5;
        const float t0 = tp[0], t1 = tp[1], t2 = tp[2], t3 = tp[3], t4 = tp[4];
        const float gx = t0*0.125f, gy = t1*0.125f, gw = t2*0.125f, gh = t3*0.125f;
        int best = 0; float bestr = -1.0f;
        #pragma unroll
        for (int cc = 0; cc < 9; cc++) {
            const float inter = fminf(gw, d_aw[cc]) * fminf(gh, d_ah[cc]);
            const float uni   = gw*gh + d_aw[cc]*d_ah[cc] - inter;
            const float rr    = inter / uni;
            if (rr > bestr) { bestr = rr; best = cc; }   // first-max tie-break
        }
        const int valid = (best >= 6 && best < 9) ? 1 : 0;
        const int gi = (int)floorf(gx);
        const int gj = (int)floorf(gy);
        // match key: a*4096 + i*64 + j  (max valid key 11507 < 12288 <= any pad-cell key)
        const int key  = valid ? (((best - 6) << 12) | (gj << 6) | gi) : 16383;
        const int meta = key | (((int)t4) << 14);
        s_box[n] = make_float4(gx - gw*0.5f, gy - gh*0.5f, gx + gw*0.5f, gy + gh*0.5f);
        s_am[n]  = make_float2(gw * gh, __int_as_float(meta));
        s_reg[n] = make_float4(gx - (float)gi, gy - (float)gj,
                               __logf(gw / d_aw[best]), __logf(gh / d_ah[best]));
        s_bls[n] = 2.0f - (t2*(1.0f/416.0f))*(t3*(1.0f/416.0f));
    }
    __syncthreads();

    // predicted boxes for both cells
    const float la_w0 = (a0 == 0) ? 1.25f  : ((a0 == 1) ? 2.0f  : 4.125f);
    const float la_h0 = (a0 == 0) ? 1.625f : ((a0 == 1) ? 3.75f : 2.875f);
    const float la_w1 = (a1t == 0) ? 1.25f  : ((a1t == 1) ? 2.0f  : 4.125f);
    const float la_h1 = (a1t == 0) ? 1.625f : ((a1t == 1) ? 3.75f : 2.875f);

    const float sx0 = sigm(z00), sy0 = sigm(z01);
    const float px0 = sx0 + (float)j0, py0 = sy0 + (float)i0;
    const float pw0 = __expf(z02) * la_w0, ph0 = __expf(z03) * la_h0;
    const float bx10 = px0 - pw0*0.5f, bx20 = px0 + pw0*0.5f;
    const float by10 = py0 - ph0*0.5f, by20 = py0 + ph0*0.5f;
    const float ab0  = pw0 * ph0;

    const float sx1 = sigm(z10), sy1 = sigm(z11);
    const float px1 = sx1 + (float)j1, py1 = sy1 + (float)i1;
    const float pw1 = __expf(z12) * la_w1, ph1 = __expf(z13) * la_h1;
    const float bx11 = px1 - pw1*0.5f, bx21 = px1 + pw1*0.5f;
    const float by11 = py1 - ph1*0.5f, by21 = py1 + ph1*0.5f;
    const float ab1  = pw1 * ph1;

    // 32-target loop: LDS reads + class-bit decode shared across both cells
    bool ig0 = false, ig1 = false;
    int  lm0 = -1,    lm1 = -1;
    unsigned long long c0lo = 0ull, c1lo = 0ull;
    unsigned int       c0hi = 0u,   c1hi = 0u;
    const int key0 = (a0  << 12) | (i0 << 6) | j0;
    const int key1 = (a1t << 12) | (i1 << 6) | j1;   // pad cells: a1t==3 -> key1>=12288, never matches
    #pragma unroll 4
    for (int n = 0; n < N_; n++) {
        const float4 tb = s_box[n];
        const float2 am = s_am[n];
        const int  meta = __float_as_int(am.y);
        const int  tkey = meta & 16383;
        const int  mcls = meta >> 14;
        const unsigned long long blo = (mcls < 64) ? (1ull << mcls) : 0ull;
        const unsigned int       bhi = (mcls >= 64) ? (1u << (mcls - 64)) : 0u;
        {
            const float iw = fmaxf(fminf(tb.z, bx20) - fmaxf(tb.x, bx10), 0.0f);
            const float ih = fmaxf(fminf(tb.w, by20) - fmaxf(tb.y, by10), 0.0f);
            const float inter = iw * ih;
            ig0 = ig0 || (3.0f*inter > am.x + ab0);   // iou > 0.5
            if (tkey == key0) { lm0 = n; c0lo |= blo; c0hi |= bhi; }  // np last-write-wins
        }
        {
            const float iw = fmaxf(fminf(tb.z, bx21) - fmaxf(tb.x, bx11), 0.0f);
            const float ih = fmaxf(fminf(tb.w, by21) - fmaxf(tb.y, by11), 0.0f);
            const float inter = iw * ih;
            ig1 = ig1 || (3.0f*inter > am.x + ab1);
            if (tkey == key1) { lm1 = n; c1lo |= blo; c1hi |= bhi; }
        }
    }
    if (!v1) lm1 = -1;   // safety: pad cells contribute nothing

    const float invB = 1.0f / (float)B_;
    float loss = 0.0f, npos = 0.0f;

    // cell0 loss
    {
        const float conf = clampp(sigm(z04));
        if (lm0 < 0) {
            if (!ig0) loss = -__logf(1.0f - conf) * invB;
        } else {
            npos = 1.0f;
            const float4 rg  = s_reg[lm0];
            const float  bls = s_bls[lm0];
            const float x = clampp(sx0);
            const float y = clampp(sy0);
            const float bx = -rg.x*__logf(x) - (1.0f - rg.x)*__logf(1.0f - x);
            const float by = -rg.y*__logf(y) - (1.0f - rg.y)*__logf(1.0f - y);
            const float dw = z02 - rg.z;
            const float dh = z03 - rg.w;
            loss = (-__logf(conf) + (bx + by + 0.5f*dw*dw + 0.5f*dh*dh) * bls) * invB;
        }
    }
    // cell1 loss (masked for pad cells)
    if (v1) {
        const float conf = clampp(sigm(z14));
        if (lm1 < 0) {
            if (!ig1) loss += -__logf(1.0f - conf) * invB;
        } else {
            npos += 1.0f;
            const float4 rg  = s_reg[lm1];
            const float  bls = s_bls[lm1];
            const float x = clampp(sx1);
            const float y = clampp(sy1);
            const float bx = -rg.x*__logf(x) - (1.0f - rg.x)*__logf(1.0f - x);
            const float by = -rg.y*__logf(y) - (1.0f - rg.y)*__logf(1.0f - y);
            const float dw = z12 - rg.z;
            const float dh = z13 - rg.w;
            loss += (-__logf(conf) + (bx + by + 0.5f*dw*dw + 0.5f*dh*dh) * bls) * invB;
        }
    }

    // wave-cooperative class BCE for each cell slot: iterate positive lanes
    // (uniform loop), 64 lanes split the 80 class-channel loads of each positive cell
    {
        const int lane = (int)(threadIdx.x & 63);
        float clsacc = 0.0f;
        #pragma unroll
        for (int slot = 0; slot < 2; slot++) {
            const int lm = (slot == 0) ? lm0 : lm1;
            const int myoff = ((slot == 0) ? off0 : off1) + 5*PLANE;
            const unsigned long long mlo = (slot == 0) ? c0lo : c1lo;
            const unsigned int       mhi = (slot == 0) ? c0hi : c1hi;
            unsigned long long pm = __ballot(lm >= 0);
            while (pm) {
                const int src = __ffsll((unsigned long long)pm) - 1;
                pm &= pm - 1;
                const int soff          = __shfl(myoff, src, 64);
                const unsigned int slo0 = (unsigned int)__shfl((int)(mlo & 0xffffffffull), src, 64);
                const unsigned int slo1 = (unsigned int)__shfl((int)(mlo >> 32), src, 64);
                const unsigned int shi  = (unsigned int)__shfl((int)mhi, src, 64);
                const float za = pred[soff + lane*PLANE];
                const float pa = clampp(sigm(za));
                const bool  ta = (lane < 32) ? ((slo0 >> lane) & 1u) : ((slo1 >> (lane - 32)) & 1u);
                clsacc += ta ? -__logf(pa) : -__logf(1.0f - pa);
                if (lane < 16) {
                    const float zb = pred[soff + (64 + lane)*PLANE];
                    const float pb = clampp(sigm(zb));
                    const bool  tb2 = (shi >> lane) & 1u;
                    clsacc += tb2 ? -__logf(pb) : -__logf(1.0f - pb);
                }
            }
        }
        loss += clsacc * invB;
    }

    // wave reduce then cross-wave via LDS
    #pragma unroll
    for (int off = 32; off > 0; off >>= 1) {
        loss += __shfl_down(loss, off, 64);
        npos += __shfl_down(npos, off, 64);
    }
    if ((threadIdx.x & 63) == 0) {
        s_red[(threadIdx.x >> 6)*2 + 0] = loss;
        s_red[(threadIdx.x >> 6)*2 + 1] = npos;
    }
    __syncthreads();
    if (threadIdx.x == 0) {
        float L = 0.0f, P = 0.0f;
        #pragma unroll
        for (int w = 0; w < 4; w++) { L += s_red[2*w]; P += s_red[2*w+1]; }
        if (use_part) part[blockIdx.x] = make_float2(L, P);
        else { atomicAdd(res + 0, L); atomicAdd(res + 1, P); }
    }
}

__launch_bounds__(256)
__global__ void kfinal(const float2* __restrict__ part, float* __restrict__ res) {
    __shared__ float s_red[8];
    float L = 0.0f, P = 0.0f;
    for (int k = threadIdx.x; k < NBLK; k += 256) {
        const float2 v = part[k];
        L += v.x; P += v.y;
    }
    #pragma unroll
    for (int off = 32; off > 0; off >>= 1) {
        L += __shfl_down(L, off, 64);
        P += __shfl_down(P, off, 64);
    }
    if ((threadIdx.x & 63) == 0) {
        s_red[(threadIdx.x >> 6)*2 + 0] = L;
        s_red[(threadIdx.x >> 6)*2 + 1] = P;
    }
    __syncthreads();
    if (threadIdx.x == 0) {
        float tl = 0.0f, tp = 0.0f;
        #pragma unroll
        for (int w = 0; w < 4; w++) { tl += s_red[2*w]; tp += s_red[2*w+1]; }
        res[0] = tl;
        res[1] = fmaxf(tp, 1.0f);
    }
}

extern "C" void kernel_launch(void* const* d_in, const int* in_sizes, int n_in,
                              void* d_out, int out_size, void* d_ws, size_t ws_size,
                              hipStream_t stream) {
    const float* pred = (const float*)d_in[0];   // (32,255,52,52) fp32
    const float* tgts = (const float*)d_in[1];   // (32,32,5) fp32
    float* res = (float*)d_out;                  // [loss, num_pos]

    if (ws_size >= (size_t)NBLK * sizeof(float2)) {
        float2* part = (float2*)d_ws;
        kmain<<<NBLK, 256, 0, stream>>>(pred, tgts, part, res, 1);
        kfinal<<<1, 256, 0, stream>>>(part, res);
    } else {
        kzero<<<1, 64, 0, stream>>>(res);
        kmain<<<NBLK, 256, 0, stream>>>(pred, tgts, nullptr, res, 0);
        kfix<<<1, 1, 0, stream>>>(res);
    }
}